// Round 4
// baseline (464.551 us; speedup 1.0000x reference)
//
#include <hip/hip_runtime.h>
#include <hip/hip_bf16.h>

typedef unsigned short u16;
typedef unsigned int u32;
typedef __bf16 bf16x8 __attribute__((ext_vector_type(8)));
typedef float f32x4 __attribute__((ext_vector_type(4)));

#define RESOLUTION 7
#define SR 2
#define SS 14
#define NSAMP 196

static __device__ __forceinline__ u16 f2bf(float f) {
    __hip_bfloat16 t = __float2bfloat16(f);
    return *reinterpret_cast<u16*>(&t);
}
static __device__ __forceinline__ float bf2f(u16 h) {
    return __uint_as_float(((u32)h) << 16);
}

// async global->LDS, 16B per lane; lds dest is wave-uniform base + lane*16
// [m97/m104-verified pattern]
static __device__ __forceinline__ void load_lds16(const u16* g, u16* l) {
    __builtin_amdgcn_global_load_lds(
        (const __attribute__((address_space(1))) unsigned int*)g,
        (__attribute__((address_space(3))) unsigned int*)l, 16, 0, 0);
}

// raw s_barrier is NOT an IR memory fence — wrap with compiler fences so
// LDS/global ops cannot be hoisted across it (race-hardening, r2->r3 fix).
static __device__ __forceinline__ void fenced_barrier() {
    asm volatile("" ::: "memory");
    __builtin_amdgcn_s_barrier();
    asm volatile("" ::: "memory");
}

// ---------------------------------------------------------------------------
// fused feat transpose: (B,C,H,W) f32 -> (B,HW,C) bf16 for all 3 levels.
// ---------------------------------------------------------------------------
__global__ __launch_bounds__(256) void transpose_feat3_kernel(
    const float* __restrict__ f0, const float* __restrict__ f1,
    const float* __restrict__ f2, u16* __restrict__ tf0,
    u16* __restrict__ tf1, u16* __restrict__ tf2) {
    int b = blockIdx.y;
    int bx = blockIdx.x;
    const float* in;
    u16* out;
    int HW, hw0;
    if (bx < 256)      { in = f0; out = tf0; HW = 16384; hw0 = bx * 64; }
    else if (bx < 320) { in = f1; out = tf1; HW = 4096;  hw0 = (bx - 256) * 64; }
    else               { in = f2; out = tf2; HW = 1024;  hw0 = (bx - 320) * 64; }

    __shared__ u16 tile[256][65];
    int hw4 = (threadIdx.x & 15) * 4;
    int cs = threadIdx.x >> 4;  // 0..15
    for (int cc = 0; cc < 256; cc += 16) {
        int c = cc + cs;
        float4 v = *(const float4*)&in[((size_t)(b * 256 + c)) * HW + hw0 + hw4];
        tile[c][hw4 + 0] = f2bf(v.x);
        tile[c][hw4 + 1] = f2bf(v.y);
        tile[c][hw4 + 2] = f2bf(v.z);
        tile[c][hw4 + 3] = f2bf(v.w);
    }
    __syncthreads();

    int ro = threadIdx.x >> 5;
    int co = (threadIdx.x & 31) * 8;
    for (int i = 0; i < 64; i += 8) {
        int hw = i + ro;
        union { uint4 v; u16 h[8]; } o;
        #pragma unroll
        for (int j = 0; j < 8; ++j) o.h[j] = tile[co + j][hw];
        *(uint4*)&out[((size_t)b * HW + hw0 + hw) * 256 + co] = o.v;
    }
}

// ---------------------------------------------------------------------------
// weight transpose: out (N=1024, K) bf16 = in (K, 1024) f32,
// optional k-permutation  k = (kp&255)*49 + (kp>>8).  float4 reads.
// ---------------------------------------------------------------------------
__global__ __launch_bounds__(256) void transpose_w_kernel(
    const float* __restrict__ in, u16* __restrict__ out, int K, int perm) {
    int kp0 = blockIdx.x * 64, n0 = blockIdx.y * 64;
    __shared__ u16 tile[64][65];

    int nn4 = (threadIdx.x & 15) * 4;
    int ks = threadIdx.x >> 4;  // 0..15
    for (int i = 0; i < 64; i += 16) {
        int kp = kp0 + ks + i;
        int k = perm ? ((kp & 255) * 49 + (kp >> 8)) : kp;
        float4 v = *(const float4*)&in[(size_t)k * 1024 + n0 + nn4];
        tile[ks + i][nn4 + 0] = f2bf(v.x);
        tile[ks + i][nn4 + 1] = f2bf(v.y);
        tile[ks + i][nn4 + 2] = f2bf(v.z);
        tile[ks + i][nn4 + 3] = f2bf(v.w);
    }
    __syncthreads();

    int nw = threadIdx.x >> 3, ko = (threadIdx.x & 7) * 8;
    for (int i = 0; i < 2; ++i) {
        int n = nw + i * 32;
        union { uint4 v; u16 h[8]; } o;
        #pragma unroll
        for (int j = 0; j < 8; ++j) o.h[j] = tile[ko + j][n];
        *(uint4*)&out[(size_t)(n0 + n) * K + kp0 + ko] = o.v;
    }
}

// ---------------------------------------------------------------------------
// concat head weights -> whT bf16 (128 rows x 1024 k; rows 100..127 zero)
// + bias (100 f32)
// ---------------------------------------------------------------------------
__global__ void head_concat_kernel(
    const float* __restrict__ cate_w, const float* __restrict__ bbox3d_w,
    const float* __restrict__ yawc_w, const float* __restrict__ yawr_w,
    const float* __restrict__ hgt_w,
    const float* __restrict__ cate_b, const float* __restrict__ bbox3d_b,
    const float* __restrict__ yawc_b, const float* __restrict__ yawr_b,
    const float* __restrict__ hgt_b,
    u16* __restrict__ whT, float* __restrict__ bh) {
    int idx = blockIdx.x * blockDim.x + threadIdx.x;
    if (idx < 128 * 1024) {
        int n = idx >> 10, k = idx & 1023;
        float v = 0.f;
        if (n < 4)        v = cate_w[k * 4 + n];
        else if (n < 22)  v = bbox3d_w[k * 18 + (n - 4)];
        else if (n < 58)  v = yawc_w[k * 36 + (n - 22)];
        else if (n < 94)  v = yawr_w[k * 36 + (n - 58)];
        else if (n < 100) v = hgt_w[k * 6 + (n - 94)];
        whT[idx] = f2bf(v);
    }
    if (idx < 100) {
        int c = idx;
        float v;
        if (c < 4)        v = cate_b[c];
        else if (c < 22)  v = bbox3d_b[c - 4];
        else if (c < 58)  v = yawc_b[c - 22];
        else if (c < 94)  v = yawr_b[c - 58];
        else              v = hgt_b[c - 94];
        bh[c] = v;
    }
}

// ---------------------------------------------------------------------------
// ROI align v3 on (B,HW,C) bf16 feats.  x row layout: k' = bin*256 + c.
// ---------------------------------------------------------------------------
__global__ __launch_bounds__(512) void roi_align_v3_kernel(
    const u16* __restrict__ tf0, const u16* __restrict__ tf1,
    const u16* __restrict__ tf2, const float* __restrict__ bbox2d,
    const int* __restrict__ anchor_id, u16* __restrict__ xb) {
    int bn = blockIdx.x;
    int b = bn >> 9;
    int tid = threadIdx.x;

    __shared__ int s_o00[NSAMP], s_o01[NSAMP], s_o10[NSAMP], s_o11[NSAMP];
    __shared__ float s_w00[NSAMP], s_w01[NSAMP], s_w10[NSAMP], s_w11[NSAMP];

    float cy = bbox2d[bn * 4 + 0], cx = bbox2d[bn * 4 + 1];
    float hh = bbox2d[bn * 4 + 2], ww = bbox2d[bn * 4 + 3];
    int lvl = anchor_id[bn] / 3;
    float scale = (lvl == 0) ? 0.25f : ((lvl == 1) ? 0.125f : 0.0625f);
    int H = (lvl == 0) ? 128 : ((lvl == 1) ? 64 : 32);
    int W = H;

    float t = cy - hh * 0.5f, l = cx - ww * 0.5f;
    float btm = cy + hh * 0.5f, r = cx + ww * 0.5f;
    float sy = t * scale - 0.5f, sx = l * scale - 0.5f;
    float bh = (btm - t) * scale * (1.0f / RESOLUTION);
    float bw = (r - l) * scale * (1.0f / RESOLUTION);

    if (tid < NSAMP) {
        int i = tid / SS, j = tid % SS;
        float gi = (i + 0.5f) * (1.0f / SR);
        float gj = (j + 0.5f) * (1.0f / SR);
        float y = sy + gi * bh, x = sx + gj * bw;
        float valid = (y > -1.0f && y < (float)H && x > -1.0f && x < (float)W)
                          ? 0.25f : 0.0f;
        y = fminf(fmaxf(y, 0.0f), (float)(H - 1));
        x = fminf(fmaxf(x, 0.0f), (float)(W - 1));
        int y0 = (int)floorf(y), x0 = (int)floorf(x);
        int y1 = min(y0 + 1, H - 1), x1 = min(x0 + 1, W - 1);
        float ly = y - (float)y0, lx = x - (float)x0;
        float hy = 1.f - ly, hx = 1.f - lx;
        s_o00[tid] = (y0 * W + x0) * 256;
        s_o01[tid] = (y0 * W + x1) * 256;
        s_o10[tid] = (y1 * W + x0) * 256;
        s_o11[tid] = (y1 * W + x1) * 256;
        s_w00[tid] = hy * hx * valid;
        s_w01[tid] = hy * lx * valid;
        s_w10[tid] = ly * hx * valid;
        s_w11[tid] = ly * lx * valid;
    }
    __syncthreads();

    const u16* fb = (lvl == 0) ? (tf0 + (size_t)b * 16384 * 256)
                  : (lvl == 1) ? (tf1 + (size_t)b * 4096 * 256)
                               : (tf2 + (size_t)b * 1024 * 256);
    int g = tid >> 5;
    int c0 = (tid & 31) * 8;
    u16* xr = xb + (size_t)bn * 12544;

    #pragma unroll
    for (int ii = 0; ii < 4; ++ii) {
        int bin = g + ii * 16;
        if (bin < 49) {
            int ph = bin / 7, pw = bin % 7;
            float a[8] = {0.f, 0.f, 0.f, 0.f, 0.f, 0.f, 0.f, 0.f};
            #pragma unroll
            for (int dy = 0; dy < SR; ++dy) {
                #pragma unroll
                for (int dx = 0; dx < SR; ++dx) {
                    int si = (ph * SR + dy) * SS + (pw * SR + dx);
                    int o00 = s_o00[si], o01 = s_o01[si];
                    int o10 = s_o10[si], o11 = s_o11[si];
                    float w00 = s_w00[si], w01 = s_w01[si];
                    float w10 = s_w10[si], w11 = s_w11[si];
                    union { uint4 v; u16 h[8]; } u0, u1, u2, u3;
                    u0.v = *(const uint4*)(fb + o00 + c0);
                    u1.v = *(const uint4*)(fb + o01 + c0);
                    u2.v = *(const uint4*)(fb + o10 + c0);
                    u3.v = *(const uint4*)(fb + o11 + c0);
                    #pragma unroll
                    for (int j = 0; j < 8; ++j) {
                        a[j] = fmaf(bf2f(u0.h[j]), w00, a[j]);
                        a[j] = fmaf(bf2f(u1.h[j]), w01, a[j]);
                        a[j] = fmaf(bf2f(u2.h[j]), w10, a[j]);
                        a[j] = fmaf(bf2f(u3.h[j]), w11, a[j]);
                    }
                }
            }
            union { uint4 v; u16 h[8]; } o;
            #pragma unroll
            for (int j = 0; j < 8; ++j) o.h[j] = f2bf(a[j]);
            *(uint4*)&xr[bin * 256 + c0] = o.v;
        }
    }
}

// ---------------------------------------------------------------------------
// output init: out(2048,100) = bias broadcast (heads GEMM accumulates on top)
// ---------------------------------------------------------------------------
__global__ void bias_out_init_kernel(float* __restrict__ out,
                                     const float* __restrict__ bh, int total) {
    int idx = blockIdx.x * blockDim.x + threadIdx.x;
    if (idx >= total) return;
    int m = idx / 100, n = idx - m * 100;
    out[idx] = bh[n];
}

// ---------------------------------------------------------------------------
// 256x256 MFMA GEMM, split-K atomic accumulate.  8 waves (2Mx4N), BK=64,
// double-buffered LDS (128 KB), T2 XOR-swizzle (bank-conflict 0, verified r2).
//
// Sync = T3+T4 counted-vmcnt schedule (m218: counted vs drain-0 = +38..73%):
//   prologue stages tiles 0,1 (16 loads/wave outstanding)
//   loop top:  s_waitcnt vmcnt(8) -> tile kt's 8 oldest loads landed, tile
//              kt+1's 8 stay in flight; fenced s_barrier publishes LDS
//              (all waves passed their own vmcnt wait).
//   4 phases:  ds_read frags -> barrier -> setprio(1)+16 MFMA+setprio(0)
//              -> barrier.  No vmcnt drain inside the loop body.
//   tile end:  after phase-3 close barrier (all waves consumed buf b into
//              registers), issue tile kt+2's 8 loads into buf b.
// Race-free: refill only after fenced close barrier; reads only after own
// vmcnt + fenced barrier; control flow block-uniform so barrier counts match.
// All raw s_barriers are compiler-fenced (raw builtin is not an IR fence).
//
// LDS swizzle (T2, rule #21): logical 16B slot s of row r at physical
// s ^ (r&7); staging keeps LDS dest linear, pre-swizzles global column.
// ---------------------------------------------------------------------------
__global__ __launch_bounds__(512) void gemm_256_splitk_kernel(
    const u16* __restrict__ A, const u16* __restrict__ BT,
    float* __restrict__ Y, int ldY, int K, int KC) {
    __shared__ __align__(16) u16 lsA[2][256 * 64];
    __shared__ __align__(16) u16 lsB[2][256 * 64];
    int m0 = blockIdx.x * 256, n0 = blockIdx.y * 256;
    int kbeg = blockIdx.z * KC;
    int tid = threadIdx.x;
    int wv = tid >> 6, lane = tid & 63;
    int wm = wv >> 2, wn = wv & 3;  // 2M x 4N wave grid; wave tile 128x64

    // staging: thread covers row sr of a 64-row chunk, physical slot sp=t&7;
    // fetches global logical slot sp ^ (sr&7).
    int sr = tid >> 3, sp = tid & 7;
    int scol = (sp ^ (sr & 7)) * 8;
    const u16* gA = A + (size_t)(m0 + sr) * K + kbeg + scol;
    const u16* gB = BT + (size_t)(n0 + sr) * K + kbeg + scol;
    int ldst = wv * 8 * 64;  // wave-uniform LDS offset within a chunk

    // fragment bases: row & 7 == lane & 7 (16-aligned row groups)
    int aRow = wm * 128 + (lane & 15);
    int bRow = wn * 64 + (lane & 15);
    int ps0 = (((lane >> 4)) ^ (lane & 7)) * 8;       // kstep 0 physical slot
    int ps1 = (((lane >> 4) | 4) ^ (lane & 7)) * 8;   // kstep 1 physical slot

    f32x4 acc[8][4] = {};
    int NT = KC >> 6;  // >= 2 for all call sites

    // prologue: stage tile 0 -> buf0, tile 1 -> buf1
    #pragma unroll
    for (int c = 0; c < 4; ++c) {
        load_lds16(gA + (size_t)(c * 64) * K, &lsA[0][c * 4096 + ldst]);
        load_lds16(gB + (size_t)(c * 64) * K, &lsB[0][c * 4096 + ldst]);
    }
    #pragma unroll
    for (int c = 0; c < 4; ++c) {
        load_lds16(gA + (size_t)(c * 64) * K + 64, &lsA[1][c * 4096 + ldst]);
        load_lds16(gB + (size_t)(c * 64) * K + 64, &lsB[1][c * 4096 + ldst]);
    }

    for (int kt = 0; kt < NT; ++kt) {
        int b = kt & 1;
        // counted wait: retire tile kt's 8 loads, keep tile kt+1's in flight
        if (kt + 1 < NT) {
            asm volatile("s_waitcnt vmcnt(8)" ::: "memory");
        } else {
            asm volatile("s_waitcnt vmcnt(0)" ::: "memory");
        }
        __builtin_amdgcn_sched_barrier(0);  // pin: nothing crosses the wait
        fenced_barrier();  // all waves' slices of buf b landed

        // hoist B fragments once per K-tile (shared by all 4 phases)
        bf16x8 bfr[4][2];
        #pragma unroll
        for (int ni = 0; ni < 4; ++ni) {
            bfr[ni][0] = *(const bf16x8*)&lsB[b][(bRow + ni * 16) * 64 + ps0];
            bfr[ni][1] = *(const bf16x8*)&lsB[b][(bRow + ni * 16) * 64 + ps1];
        }
        #pragma unroll
        for (int q = 0; q < 4; ++q) {  // quadrant = 2 m-frags x 4 n-frags
            bf16x8 af[2][2];
            #pragma unroll
            for (int m2 = 0; m2 < 2; ++m2) {
                int rr = (aRow + (q * 2 + m2) * 16) * 64;
                af[m2][0] = *(const bf16x8*)&lsA[b][rr + ps0];
                af[m2][1] = *(const bf16x8*)&lsA[b][rr + ps1];
            }
            fenced_barrier();  // phase open
            __builtin_amdgcn_s_setprio(1);
            #pragma unroll
            for (int m2 = 0; m2 < 2; ++m2) {
                #pragma unroll
                for (int ni = 0; ni < 4; ++ni) {
                    acc[q * 2 + m2][ni] = __builtin_amdgcn_mfma_f32_16x16x32_bf16(
                        af[m2][0], bfr[ni][0], acc[q * 2 + m2][ni], 0, 0, 0);
                    acc[q * 2 + m2][ni] = __builtin_amdgcn_mfma_f32_16x16x32_bf16(
                        af[m2][1], bfr[ni][1], acc[q * 2 + m2][ni], 0, 0, 0);
                }
            }
            __builtin_amdgcn_s_setprio(0);
            fenced_barrier();  // phase close
        }
        // phase-3 close barrier passed: all waves consumed buf b -> refill it
        if (kt + 2 < NT) {
            int ko = (kt + 2) << 6;
            #pragma unroll
            for (int c = 0; c < 4; ++c) {
                load_lds16(gA + (size_t)(c * 64) * K + ko, &lsA[b][c * 4096 + ldst]);
                load_lds16(gB + (size_t)(c * 64) * K + ko, &lsB[b][c * 4096 + ldst]);
            }
        }
    }

    // D layout: col=lane&15, row=(lane>>4)*4+reg  (m89-verified)
    int col = lane & 15, qr = lane >> 4;
    #pragma unroll
    for (int mi = 0; mi < 8; ++mi) {
        #pragma unroll
        for (int ni = 0; ni < 4; ++ni) {
            int nn = n0 + wn * 64 + ni * 16 + col;
            #pragma unroll
            for (int rg = 0; rg < 4; ++rg) {
                int mm = m0 + wm * 128 + mi * 16 + qr * 4 + rg;
                unsafeAtomicAdd(&Y[(size_t)mm * ldY + nn], acc[mi][ni][rg]);
            }
        }
    }
}

// ---------------------------------------------------------------------------
// 128x128 MFMA GEMM, split-K + atomic accumulation (kept for fc2 / heads:
// K too short for the 256^2 pipeline).  ldY = row stride, nmax = col bound.
// ---------------------------------------------------------------------------
__global__ __launch_bounds__(256) void gemm_splitk_kernel(
    const u16* __restrict__ A, const u16* __restrict__ BT,
    float* __restrict__ Y, int ldY, int nmax, int K, int KC) {
    __shared__ u16 la[2][128 * 32];
    __shared__ u16 lb[2][128 * 32];
    int m0 = blockIdx.x * 128;
    int n0 = blockIdx.y * 128;
    int kbeg = blockIdx.z * KC;
    int tid = threadIdx.x;
    int w = tid >> 6, lane = tid & 63;
    int wm = (w >> 1) * 64, wn = (w & 1) * 64;

    int idx1 = tid + 256;
    const u16* gA0 = A + (size_t)(m0 + (tid >> 2)) * K + (tid & 3) * 8 + kbeg;
    const u16* gA1 = A + (size_t)(m0 + (idx1 >> 2)) * K + (idx1 & 3) * 8 + kbeg;
    const u16* gB0 = BT + (size_t)(n0 + (tid >> 2)) * K + (tid & 3) * 8 + kbeg;
    const u16* gB1 = BT + (size_t)(n0 + (idx1 >> 2)) * K + (idx1 & 3) * 8 + kbeg;
    u16* lA0a = la[0] + w * 512;
    u16* lA1a = la[0] + 2048 + w * 512;
    u16* lB0a = lb[0] + w * 512;
    u16* lB1a = lb[0] + 2048 + w * 512;
    u16* lA0b = la[1] + w * 512;
    u16* lA1b = la[1] + 2048 + w * 512;
    u16* lB0b = lb[1] + w * 512;
    u16* lB1b = lb[1] + 2048 + w * 512;

    f32x4 acc[4][4] = {};
    int row16 = lane & 15, q8 = (lane >> 4) * 8;

    for (int k0 = 0; k0 < KC; k0 += 64) {
        load_lds16(gA0 + k0, lA0a);
        load_lds16(gA1 + k0, lA1a);
        load_lds16(gB0 + k0, lB0a);
        load_lds16(gB1 + k0, lB1a);
        load_lds16(gA0 + k0 + 32, lA0b);
        load_lds16(gA1 + k0 + 32, lA1b);
        load_lds16(gB0 + k0 + 32, lB0b);
        load_lds16(gB1 + k0 + 32, lB1b);
        __syncthreads();

        #pragma unroll
        for (int h = 0; h < 2; ++h) {
            bf16x8 af[4], bf[4];
            #pragma unroll
            for (int tm = 0; tm < 4; ++tm)
                af[tm] = *(const bf16x8*)&la[h][(wm + tm * 16 + row16) * 32 + q8];
            #pragma unroll
            for (int tn = 0; tn < 4; ++tn)
                bf[tn] = *(const bf16x8*)&lb[h][(wn + tn * 16 + row16) * 32 + q8];
            #pragma unroll
            for (int tm = 0; tm < 4; ++tm)
                #pragma unroll
                for (int tn = 0; tn < 4; ++tn)
                    acc[tm][tn] = __builtin_amdgcn_mfma_f32_16x16x32_bf16(
                        af[tm], bf[tn], acc[tm][tn], 0, 0, 0);
        }
        __syncthreads();
    }

    int col = lane & 15, qr = lane >> 4;
    #pragma unroll
    for (int tm = 0; tm < 4; ++tm) {
        #pragma unroll
        for (int tn = 0; tn < 4; ++tn) {
            int nn = n0 + wn + tn * 16 + col;
            if (nn < nmax) {
                #pragma unroll
                for (int rg = 0; rg < 4; ++rg) {
                    int mm = m0 + wm + tm * 16 + qr * 4 + rg;
                    unsafeAtomicAdd(&Y[(size_t)mm * ldY + nn], acc[tm][tn][rg]);
                }
            }
        }
    }
}

// ---------------------------------------------------------------------------
// BN stats stage 1: partial sum/sumsq per 32-row chunk.
// ---------------------------------------------------------------------------
__global__ __launch_bounds__(256) void bn_stats_part_kernel(
    const float* __restrict__ y, float* __restrict__ part, int N) {
    int c4 = blockIdx.x * 256 + (threadIdx.x & 63) * 4;
    int rg = threadIdx.x >> 6;
    int r0 = blockIdx.y * 32;
    float4 s = make_float4(0.f, 0.f, 0.f, 0.f);
    float4 q = make_float4(0.f, 0.f, 0.f, 0.f);
    for (int i = 0; i < 8; ++i) {
        int r = r0 + rg + i * 4;
        float4 v = *(const float4*)&y[(size_t)r * N + c4];
        s.x += v.x; s.y += v.y; s.z += v.z; s.w += v.w;
        q.x += v.x * v.x; q.y += v.y * v.y; q.z += v.z * v.z; q.w += v.w * v.w;
    }
    __shared__ float4 ls[4][64], lq[4][64];
    ls[rg][threadIdx.x & 63] = s;
    lq[rg][threadIdx.x & 63] = q;
    __syncthreads();
    if (rg == 0) {
        int cx = threadIdx.x & 63;
        #pragma unroll
        for (int g = 1; g < 4; ++g) {
            float4 a = ls[g][cx], b = lq[g][cx];
            s.x += a.x; s.y += a.y; s.z += a.z; s.w += a.w;
            q.x += b.x; q.y += b.y; q.z += b.z; q.w += b.w;
        }
        float* po = part + (size_t)blockIdx.y * 2048;
        *(float4*)&po[c4] = s;
        *(float4*)&po[1024 + c4] = q;
    }
}

// ---------------------------------------------------------------------------
// BN stats stage 2: reduce chunks -> mean, rstd.
// ---------------------------------------------------------------------------
__global__ __launch_bounds__(256) void bn_stats_final_kernel(
    const float* __restrict__ part, float* __restrict__ stats, int M, int nchunk) {
    int col = blockIdx.x * 256 + threadIdx.x;
    float s = 0.f, q = 0.f;
    for (int ch = 0; ch < nchunk; ++ch) {
        s += part[(size_t)ch * 2048 + col];
        q += part[(size_t)ch * 2048 + 1024 + col];
    }
    float mean = s / (float)M;
    float var = q / (float)M - mean * mean;
    stats[col] = mean;
    stats[1024 + col] = rsqrtf(var + 1e-5f);
}

// ---------------------------------------------------------------------------
// BN apply + relu -> bf16, float4-vectorized, optionally zeroing y.
// ---------------------------------------------------------------------------
__global__ void bn_apply_kernel(float* __restrict__ y,
                                const float* __restrict__ stats,
                                const float* __restrict__ g,
                                const float* __restrict__ b,
                                u16* __restrict__ xo, int total4, int zero_y) {
    int idx = blockIdx.x * blockDim.x + threadIdx.x;
    if (idx >= total4) return;
    int e0 = idx * 4;
    int col = e0 & 1023;
    float4 v = *(const float4*)&y[e0];
    float4 mu = *(const float4*)&stats[col];
    float4 rs = *(const float4*)&stats[1024 + col];
    float4 gg = *(const float4*)&g[col];
    float4 bb = *(const float4*)&b[col];
    ushort4 o;
    o.x = f2bf(fmaxf((v.x - mu.x) * rs.x * gg.x + bb.x, 0.f));
    o.y = f2bf(fmaxf((v.y - mu.y) * rs.y * gg.y + bb.y, 0.f));
    o.z = f2bf(fmaxf((v.z - mu.z) * rs.z * gg.z + bb.z, 0.f));
    o.w = f2bf(fmaxf((v.w - mu.w) * rs.w * gg.w + bb.w, 0.f));
    *(ushort4*)&xo[e0] = o;
    if (zero_y)
        *(float4*)&y[e0] = make_float4(0.f, 0.f, 0.f, 0.f);
}

// ---------------------------------------------------------------------------
extern "C" void kernel_launch(void* const* d_in, const int* in_sizes, int n_in,
                              void* d_out, int out_size, void* d_ws, size_t ws_size,
                              hipStream_t stream) {
    const float* feat0   = (const float*)d_in[0];
    const float* feat1   = (const float*)d_in[1];
    const float* feat2   = (const float*)d_in[2];
    const float* bbox2d  = (const float*)d_in[3];
    const int*   anchor  = (const int*)d_in[4];
    const float* fc1_w   = (const float*)d_in[5];
    const float* bn1_g   = (const float*)d_in[7];
    const float* bn1_b   = (const float*)d_in[8];
    const float* fc2_w   = (const float*)d_in[9];
    const float* bn2_g   = (const float*)d_in[11];
    const float* bn2_b   = (const float*)d_in[12];
    const float* cate_w  = (const float*)d_in[13];
    const float* cate_b  = (const float*)d_in[14];
    const float* bbox3d_w= (const float*)d_in[15];
    const float* bbox3d_b= (const float*)d_in[16];
    const float* yawc_w  = (const float*)d_in[17];
    const float* yawc_b  = (const float*)d_in[18];
    const float* yawr_w  = (const float*)d_in[19];
    const float* yawr_b  = (const float*)d_in[20];
    const float* hgt_w   = (const float*)d_in[21];
    const float* hgt_b   = (const float*)d_in[22];

    const int B = 4, N = 512, FC = 1024;
    const int M = B * N;   // 2048
    const int K1 = 12544;  // 256*49

    // workspace layout (tf* aliased with post-ROI buffers; disjoint lifetimes)
    char* base = (char*)d_ws;
    u16* xb = (u16*)base;                              // 51,380,224 B
    char* ub = base + 51380224;                        // union, 44,040,192 B
    u16* tf0 = (u16*)ub;                               // 33,554,432
    u16* tf1 = (u16*)(ub + 33554432);                  //  8,388,608
    u16* tf2 = (u16*)(ub + 41943040);                  //  2,097,152
    u16* w1t = (u16*)ub;                               // 25,690,112
    u16* w2t = (u16*)(ub + 25690112);                  //  2,097,152
    float* y   = (float*)(ub + 27787264);              //  8,388,608
    u16* x1b = (u16*)(ub + 36175872);                  //  4,194,304 (end 40,370,176)
    float* part = (float*)(ub + 40370176);             //    524,288 (end 40,894,464)
    char* tail = ub + 44040192;
    float* stats = (float*)tail;                       // 8 KB
    u16*   whT   = (u16*)(tail + 8192);                // 262,144 (128x1024 bf16)
    float* bhd   = (float*)(tail + 8192 + 262144);     // 512
    float* outp  = (float*)d_out;

    // 1. head weight concat -> whT bf16 + bias (independent)
    head_concat_kernel<<<(128 * 1024 + 255) / 256, 256, 0, stream>>>(
        cate_w, bbox3d_w, yawc_w, yawr_w, hgt_w,
        cate_b, bbox3d_b, yawc_b, yawr_b, hgt_b, whT, bhd);

    // 2. fused feature layout transform (B,C,H,W)f32 -> (B,HW,C)bf16
    transpose_feat3_kernel<<<dim3(336, B), 256, 0, stream>>>(
        feat0, feat1, feat2, tf0, tf1, tf2);

    // 3. ROI align -> x bf16 (M, K1), k' = bin*256 + c layout
    roi_align_v3_kernel<<<M, 512, 0, stream>>>(tf0, tf1, tf2, bbox2d, anchor, xb);

    // 4. weight transposes (overwrite tf* region — after roi)
    transpose_w_kernel<<<dim3(K1 / 64, FC / 64), 256, 0, stream>>>(fc1_w, w1t, K1, 1);
    transpose_w_kernel<<<dim3(FC / 64, FC / 64), 256, 0, stream>>>(fc2_w, w2t, FC, 0);

    // 5. fc1: 256^2 counted-vmcnt kernel, split-K=7 -> 224 blocks (1/CU) + BN1
    hipMemsetAsync(y, 0, (size_t)M * FC * 4, stream);
    gemm_256_splitk_kernel<<<dim3(M / 256, FC / 256, 7), 512, 0, stream>>>(
        xb, w1t, y, FC, K1, K1 / 7);
    bn_stats_part_kernel<<<dim3(FC / 256, M / 32), 256, 0, stream>>>(y, part, FC);
    bn_stats_final_kernel<<<FC / 256, 256, 0, stream>>>(part, stats, M, M / 32);
    bn_apply_kernel<<<(M * FC / 4 + 255) / 256, 256, 0, stream>>>(
        y, stats, bn1_g, bn1_b, x1b, M * FC / 4, 1);  // zero y for fc2

    // 6. fc2 (split-K=4, 128^2 kernel: K=1024 too short for deep pipeline) + BN2
    gemm_splitk_kernel<<<dim3(M / 128, FC / 128, 4), 256, 0, stream>>>(
        x1b, w2t, y, FC, FC, FC, FC / 4);
    bn_stats_part_kernel<<<dim3(FC / 256, M / 32), 256, 0, stream>>>(y, part, FC);
    bn_stats_final_kernel<<<FC / 256, 256, 0, stream>>>(part, stats, M, M / 32);
    bn_apply_kernel<<<(M * FC / 4 + 255) / 256, 256, 0, stream>>>(
        y, stats, bn2_g, bn2_b, x1b, M * FC / 4, 0);

    // 7. heads: out = bias; out += (x1b @ whT^T)[:, :100] directly into d_out.
    bias_out_init_kernel<<<(M * 100 + 255) / 256, 256, 0, stream>>>(outp, bhd, M * 100);
    gemm_splitk_kernel<<<dim3(M / 128, 1, 16), 256, 0, stream>>>(
        x1b, whT, outp, 100, 100, FC, FC / 16);
}

// Round 6
// 441.134 us; speedup vs baseline: 1.0531x; 1.0531x over previous
//
#include <hip/hip_runtime.h>
#include <hip/hip_bf16.h>

typedef unsigned short u16;
typedef unsigned int u32;
typedef __bf16 bf16x8 __attribute__((ext_vector_type(8)));
typedef float f32x4 __attribute__((ext_vector_type(4)));

#define RESOLUTION 7
#define SR 2
#define SS 14
#define NSAMP 196

static __device__ __forceinline__ u16 f2bf(float f) {
    __hip_bfloat16 t = __float2bfloat16(f);
    return *reinterpret_cast<u16*>(&t);
}
static __device__ __forceinline__ float bf2f(u16 h) {
    return __uint_as_float(((u32)h) << 16);
}

// async global->LDS, 16B per lane; lds dest is wave-uniform base + lane*16
// [m97/m104-verified pattern]
static __device__ __forceinline__ void load_lds16(const u16* g, u16* l) {
    __builtin_amdgcn_global_load_lds(
        (const __attribute__((address_space(1))) unsigned int*)g,
        (__attribute__((address_space(3))) unsigned int*)l, 16, 0, 0);
}

// ---------------------------------------------------------------------------
// fused feat transpose: (B,C,H,W) f32 -> (B,HW,C) bf16 for all 3 levels.
// ---------------------------------------------------------------------------
__global__ __launch_bounds__(256) void transpose_feat3_kernel(
    const float* __restrict__ f0, const float* __restrict__ f1,
    const float* __restrict__ f2, u16* __restrict__ tf0,
    u16* __restrict__ tf1, u16* __restrict__ tf2) {
    int b = blockIdx.y;
    int bx = blockIdx.x;
    const float* in;
    u16* out;
    int HW, hw0;
    if (bx < 256)      { in = f0; out = tf0; HW = 16384; hw0 = bx * 64; }
    else if (bx < 320) { in = f1; out = tf1; HW = 4096;  hw0 = (bx - 256) * 64; }
    else               { in = f2; out = tf2; HW = 1024;  hw0 = (bx - 320) * 64; }

    __shared__ u16 tile[256][65];
    int hw4 = (threadIdx.x & 15) * 4;
    int cs = threadIdx.x >> 4;  // 0..15
    for (int cc = 0; cc < 256; cc += 16) {
        int c = cc + cs;
        float4 v = *(const float4*)&in[((size_t)(b * 256 + c)) * HW + hw0 + hw4];
        tile[c][hw4 + 0] = f2bf(v.x);
        tile[c][hw4 + 1] = f2bf(v.y);
        tile[c][hw4 + 2] = f2bf(v.z);
        tile[c][hw4 + 3] = f2bf(v.w);
    }
    __syncthreads();

    int ro = threadIdx.x >> 5;
    int co = (threadIdx.x & 31) * 8;
    for (int i = 0; i < 64; i += 8) {
        int hw = i + ro;
        union { uint4 v; u16 h[8]; } o;
        #pragma unroll
        for (int j = 0; j < 8; ++j) o.h[j] = tile[co + j][hw];
        *(uint4*)&out[((size_t)b * HW + hw0 + hw) * 256 + co] = o.v;
    }
}

// ---------------------------------------------------------------------------
// merged weight transpose (fc1_w with k-perm + fc2_w) -> bf16 (N,K) layouts.
// Also zeroes y (fc1 accumulator) — replaces the hipMemsetAsync launch.
// bx<196: fc1_w slice; bx>=196: fc2_w slice.
// ---------------------------------------------------------------------------
__global__ __launch_bounds__(256) void transpose_w2_kernel(
    const float* __restrict__ in1, const float* __restrict__ in2,
    u16* __restrict__ w1t, u16* __restrict__ w2t,
    float4* __restrict__ y4) {
    int bx = blockIdx.x, n0 = blockIdx.y * 64;
    const float* in;
    u16* out;
    int K, kp0, perm;
    if (bx < 196) { in = in1; out = w1t; K = 12544; kp0 = bx * 64; perm = 1; }
    else          { in = in2; out = w2t; K = 1024;  kp0 = (bx - 196) * 64; perm = 0; }

    // side duty: zero y (2048x1024 f32 = 524288 float4), each fid unique
    int fid = (blockIdx.y * 212 + bx) * 256 + threadIdx.x;
    if (fid < 524288) y4[fid] = make_float4(0.f, 0.f, 0.f, 0.f);

    __shared__ u16 tile[64][65];
    int nn4 = (threadIdx.x & 15) * 4;
    int ks = threadIdx.x >> 4;  // 0..15
    for (int i = 0; i < 64; i += 16) {
        int kp = kp0 + ks + i;
        int k = perm ? ((kp & 255) * 49 + (kp >> 8)) : kp;
        float4 v = *(const float4*)&in[(size_t)k * 1024 + n0 + nn4];
        tile[ks + i][nn4 + 0] = f2bf(v.x);
        tile[ks + i][nn4 + 1] = f2bf(v.y);
        tile[ks + i][nn4 + 2] = f2bf(v.z);
        tile[ks + i][nn4 + 3] = f2bf(v.w);
    }
    __syncthreads();

    int nw = threadIdx.x >> 3, ko = (threadIdx.x & 7) * 8;
    for (int i = 0; i < 2; ++i) {
        int n = nw + i * 32;
        union { uint4 v; u16 h[8]; } o;
        #pragma unroll
        for (int j = 0; j < 8; ++j) o.h[j] = tile[ko + j][n];
        *(uint4*)&out[(size_t)(n0 + n) * K + kp0 + ko] = o.v;
    }
}

// ---------------------------------------------------------------------------
// head prep: concat head weights -> whT bf16 (128 x 1024; rows 100..127 zero)
// AND write bias broadcast directly into out(2048,100) (heads GEMM
// accumulates on top).  Merges old head_concat + bias_out_init.
// ---------------------------------------------------------------------------
__global__ void head_prep_kernel(
    const float* __restrict__ cate_w, const float* __restrict__ bbox3d_w,
    const float* __restrict__ yawc_w, const float* __restrict__ yawr_w,
    const float* __restrict__ hgt_w,
    const float* __restrict__ cate_b, const float* __restrict__ bbox3d_b,
    const float* __restrict__ yawc_b, const float* __restrict__ yawr_b,
    const float* __restrict__ hgt_b,
    u16* __restrict__ whT, float* __restrict__ outp) {
    int idx = blockIdx.x * blockDim.x + threadIdx.x;
    if (idx < 128 * 1024) {
        int n = idx >> 10, k = idx & 1023;
        float v = 0.f;
        if (n < 4)        v = cate_w[k * 4 + n];
        else if (n < 22)  v = bbox3d_w[k * 18 + (n - 4)];
        else if (n < 58)  v = yawc_w[k * 36 + (n - 22)];
        else if (n < 94)  v = yawr_w[k * 36 + (n - 58)];
        else if (n < 100) v = hgt_w[k * 6 + (n - 94)];
        whT[idx] = f2bf(v);
    }
    if (idx < 2048 * 100) {
        int c = idx - (idx / 100) * 100;
        float v;
        if (c < 4)        v = cate_b[c];
        else if (c < 22)  v = bbox3d_b[c - 4];
        else if (c < 58)  v = yawc_b[c - 22];
        else if (c < 94)  v = yawr_b[c - 58];
        else              v = hgt_b[c - 94];
        outp[idx] = v;
    }
}

// ---------------------------------------------------------------------------
// ROI align v3 on (B,HW,C) bf16 feats.  x row layout: k' = bin*256 + c.
// ---------------------------------------------------------------------------
__global__ __launch_bounds__(512) void roi_align_v3_kernel(
    const u16* __restrict__ tf0, const u16* __restrict__ tf1,
    const u16* __restrict__ tf2, const float* __restrict__ bbox2d,
    const int* __restrict__ anchor_id, u16* __restrict__ xb) {
    int bn = blockIdx.x;
    int b = bn >> 9;
    int tid = threadIdx.x;

    __shared__ int s_o00[NSAMP], s_o01[NSAMP], s_o10[NSAMP], s_o11[NSAMP];
    __shared__ float s_w00[NSAMP], s_w01[NSAMP], s_w10[NSAMP], s_w11[NSAMP];

    float cy = bbox2d[bn * 4 + 0], cx = bbox2d[bn * 4 + 1];
    float hh = bbox2d[bn * 4 + 2], ww = bbox2d[bn * 4 + 3];
    int lvl = anchor_id[bn] / 3;
    float scale = (lvl == 0) ? 0.25f : ((lvl == 1) ? 0.125f : 0.0625f);
    int H = (lvl == 0) ? 128 : ((lvl == 1) ? 64 : 32);
    int W = H;

    float t = cy - hh * 0.5f, l = cx - ww * 0.5f;
    float btm = cy + hh * 0.5f, r = cx + ww * 0.5f;
    float sy = t * scale - 0.5f, sx = l * scale - 0.5f;
    float bh = (btm - t) * scale * (1.0f / RESOLUTION);
    float bw = (r - l) * scale * (1.0f / RESOLUTION);

    if (tid < NSAMP) {
        int i = tid / SS, j = tid % SS;
        float gi = (i + 0.5f) * (1.0f / SR);
        float gj = (j + 0.5f) * (1.0f / SR);
        float y = sy + gi * bh, x = sx + gj * bw;
        float valid = (y > -1.0f && y < (float)H && x > -1.0f && x < (float)W)
                          ? 0.25f : 0.0f;
        y = fminf(fmaxf(y, 0.0f), (float)(H - 1));
        x = fminf(fmaxf(x, 0.0f), (float)(W - 1));
        int y0 = (int)floorf(y), x0 = (int)floorf(x);
        int y1 = min(y0 + 1, H - 1), x1 = min(x0 + 1, W - 1);
        float ly = y - (float)y0, lx = x - (float)x0;
        float hy = 1.f - ly, hx = 1.f - lx;
        s_o00[tid] = (y0 * W + x0) * 256;
        s_o01[tid] = (y0 * W + x1) * 256;
        s_o10[tid] = (y1 * W + x0) * 256;
        s_o11[tid] = (y1 * W + x1) * 256;
        s_w00[tid] = hy * hx * valid;
        s_w01[tid] = hy * lx * valid;
        s_w10[tid] = ly * hx * valid;
        s_w11[tid] = ly * lx * valid;
    }
    __syncthreads();

    const u16* fb = (lvl == 0) ? (tf0 + (size_t)b * 16384 * 256)
                  : (lvl == 1) ? (tf1 + (size_t)b * 4096 * 256)
                               : (tf2 + (size_t)b * 1024 * 256);
    int g = tid >> 5;
    int c0 = (tid & 31) * 8;
    u16* xr = xb + (size_t)bn * 12544;

    #pragma unroll
    for (int ii = 0; ii < 4; ++ii) {
        int bin = g + ii * 16;
        if (bin < 49) {
            int ph = bin / 7, pw = bin % 7;
            float a[8] = {0.f, 0.f, 0.f, 0.f, 0.f, 0.f, 0.f, 0.f};
            #pragma unroll
            for (int dy = 0; dy < SR; ++dy) {
                #pragma unroll
                for (int dx = 0; dx < SR; ++dx) {
                    int si = (ph * SR + dy) * SS + (pw * SR + dx);
                    int o00 = s_o00[si], o01 = s_o01[si];
                    int o10 = s_o10[si], o11 = s_o11[si];
                    float w00 = s_w00[si], w01 = s_w01[si];
                    float w10 = s_w10[si], w11 = s_w11[si];
                    union { uint4 v; u16 h[8]; } u0, u1, u2, u3;
                    u0.v = *(const uint4*)(fb + o00 + c0);
                    u1.v = *(const uint4*)(fb + o01 + c0);
                    u2.v = *(const uint4*)(fb + o10 + c0);
                    u3.v = *(const uint4*)(fb + o11 + c0);
                    #pragma unroll
                    for (int j = 0; j < 8; ++j) {
                        a[j] = fmaf(bf2f(u0.h[j]), w00, a[j]);
                        a[j] = fmaf(bf2f(u1.h[j]), w01, a[j]);
                        a[j] = fmaf(bf2f(u2.h[j]), w10, a[j]);
                        a[j] = fmaf(bf2f(u3.h[j]), w11, a[j]);
                    }
                }
            }
            union { uint4 v; u16 h[8]; } o;
            #pragma unroll
            for (int j = 0; j < 8; ++j) o.h[j] = f2bf(a[j]);
            *(uint4*)&xr[bin * 256 + c0] = o.v;
        }
    }
}

// ---------------------------------------------------------------------------
// 128x128 MFMA GEMM, split-K + atomic accumulation, BK=64 double-stage:
// 32 MFMAs per barrier pair; 32 KB LDS.  (round-0 structure — best measured
// fc1 config; 256^2 pipelined variants measured slower, reverted.)
// ldY = output row stride, nmax = output col bound (heads writes 100 of 128).
// ---------------------------------------------------------------------------
__global__ __launch_bounds__(256) void gemm_splitk_kernel(
    const u16* __restrict__ A, const u16* __restrict__ BT,
    float* __restrict__ Y, int ldY, int nmax, int K, int KC) {
    __shared__ u16 la[2][128 * 32];
    __shared__ u16 lb[2][128 * 32];
    int m0 = blockIdx.x * 128;
    int n0 = blockIdx.y * 128;
    int kbeg = blockIdx.z * KC;
    int tid = threadIdx.x;
    int w = tid >> 6, lane = tid & 63;
    int wm = (w >> 1) * 64, wn = (w & 1) * 64;

    int idx1 = tid + 256;
    const u16* gA0 = A + (size_t)(m0 + (tid >> 2)) * K + (tid & 3) * 8 + kbeg;
    const u16* gA1 = A + (size_t)(m0 + (idx1 >> 2)) * K + (idx1 & 3) * 8 + kbeg;
    const u16* gB0 = BT + (size_t)(n0 + (tid >> 2)) * K + (tid & 3) * 8 + kbeg;
    const u16* gB1 = BT + (size_t)(n0 + (idx1 >> 2)) * K + (idx1 & 3) * 8 + kbeg;
    u16* lA0a = la[0] + w * 512;
    u16* lA1a = la[0] + 2048 + w * 512;
    u16* lB0a = lb[0] + w * 512;
    u16* lB1a = lb[0] + 2048 + w * 512;
    u16* lA0b = la[1] + w * 512;
    u16* lA1b = la[1] + 2048 + w * 512;
    u16* lB0b = lb[1] + w * 512;
    u16* lB1b = lb[1] + 2048 + w * 512;

    f32x4 acc[4][4] = {};
    int row16 = lane & 15, q8 = (lane >> 4) * 8;

    for (int k0 = 0; k0 < KC; k0 += 64) {
        load_lds16(gA0 + k0, lA0a);
        load_lds16(gA1 + k0, lA1a);
        load_lds16(gB0 + k0, lB0a);
        load_lds16(gB1 + k0, lB1a);
        load_lds16(gA0 + k0 + 32, lA0b);
        load_lds16(gA1 + k0 + 32, lA1b);
        load_lds16(gB0 + k0 + 32, lB0b);
        load_lds16(gB1 + k0 + 32, lB1b);
        __syncthreads();

        #pragma unroll
        for (int h = 0; h < 2; ++h) {
            bf16x8 af[4], bf[4];
            #pragma unroll
            for (int tm = 0; tm < 4; ++tm)
                af[tm] = *(const bf16x8*)&la[h][(wm + tm * 16 + row16) * 32 + q8];
            #pragma unroll
            for (int tn = 0; tn < 4; ++tn)
                bf[tn] = *(const bf16x8*)&lb[h][(wn + tn * 16 + row16) * 32 + q8];
            #pragma unroll
            for (int tm = 0; tm < 4; ++tm)
                #pragma unroll
                for (int tn = 0; tn < 4; ++tn)
                    acc[tm][tn] = __builtin_amdgcn_mfma_f32_16x16x32_bf16(
                        af[tm], bf[tn], acc[tm][tn], 0, 0, 0);
        }
        __syncthreads();
    }

    // D layout: col=lane&15, row=(lane>>4)*4+reg  (m89-verified)
    int col = lane & 15, qr = lane >> 4;
    #pragma unroll
    for (int tm = 0; tm < 4; ++tm) {
        #pragma unroll
        for (int tn = 0; tn < 4; ++tn) {
            int nn = n0 + wn + tn * 16 + col;
            if (nn < nmax) {
                #pragma unroll
                for (int rg = 0; rg < 4; ++rg) {
                    int mm = m0 + wm + tm * 16 + qr * 4 + rg;
                    unsafeAtomicAdd(&Y[(size_t)mm * ldY + nn], acc[tm][tn][rg]);
                }
            }
        }
    }
}

// ---------------------------------------------------------------------------
// BN stats stage 1: partial sum/sumsq per 32-row chunk.
// ---------------------------------------------------------------------------
__global__ __launch_bounds__(256) void bn_stats_part_kernel(
    const float* __restrict__ y, float* __restrict__ part, int N) {
    int c4 = blockIdx.x * 256 + (threadIdx.x & 63) * 4;
    int rg = threadIdx.x >> 6;
    int r0 = blockIdx.y * 32;
    float4 s = make_float4(0.f, 0.f, 0.f, 0.f);
    float4 q = make_float4(0.f, 0.f, 0.f, 0.f);
    for (int i = 0; i < 8; ++i) {
        int r = r0 + rg + i * 4;
        float4 v = *(const float4*)&y[(size_t)r * N + c4];
        s.x += v.x; s.y += v.y; s.z += v.z; s.w += v.w;
        q.x += v.x * v.x; q.y += v.y * v.y; q.z += v.z * v.z; q.w += v.w * v.w;
    }
    __shared__ float4 ls[4][64], lq[4][64];
    ls[rg][threadIdx.x & 63] = s;
    lq[rg][threadIdx.x & 63] = q;
    __syncthreads();
    if (rg == 0) {
        int cx = threadIdx.x & 63;
        #pragma unroll
        for (int g = 1; g < 4; ++g) {
            float4 a = ls[g][cx], b = lq[g][cx];
            s.x += a.x; s.y += a.y; s.z += a.z; s.w += a.w;
            q.x += b.x; q.y += b.y; q.z += b.z; q.w += b.w;
        }
        float* po = part + (size_t)blockIdx.y * 2048;
        *(float4*)&po[c4] = s;
        *(float4*)&po[1024 + c4] = q;
    }
}

// ---------------------------------------------------------------------------
// BN stats stage 2: reduce chunks -> mean, rstd.
// ---------------------------------------------------------------------------
__global__ __launch_bounds__(256) void bn_stats_final_kernel(
    const float* __restrict__ part, float* __restrict__ stats, int M, int nchunk) {
    int col = blockIdx.x * 256 + threadIdx.x;
    float s = 0.f, q = 0.f;
    for (int ch = 0; ch < nchunk; ++ch) {
        s += part[(size_t)ch * 2048 + col];
        q += part[(size_t)ch * 2048 + 1024 + col];
    }
    float mean = s / (float)M;
    float var = q / (float)M - mean * mean;
    stats[col] = mean;
    stats[1024 + col] = rsqrtf(var + 1e-5f);
}

// ---------------------------------------------------------------------------
// BN apply + relu -> bf16, float4-vectorized, optionally zeroing y.
// ---------------------------------------------------------------------------
__global__ void bn_apply_kernel(float* __restrict__ y,
                                const float* __restrict__ stats,
                                const float* __restrict__ g,
                                const float* __restrict__ b,
                                u16* __restrict__ xo, int total4, int zero_y) {
    int idx = blockIdx.x * blockDim.x + threadIdx.x;
    if (idx >= total4) return;
    int e0 = idx * 4;
    int col = e0 & 1023;
    float4 v = *(const float4*)&y[e0];
    float4 mu = *(const float4*)&stats[col];
    float4 rs = *(const float4*)&stats[1024 + col];
    float4 gg = *(const float4*)&g[col];
    float4 bb = *(const float4*)&b[col];
    ushort4 o;
    o.x = f2bf(fmaxf((v.x - mu.x) * rs.x * gg.x + bb.x, 0.f));
    o.y = f2bf(fmaxf((v.y - mu.y) * rs.y * gg.y + bb.y, 0.f));
    o.z = f2bf(fmaxf((v.z - mu.z) * rs.z * gg.z + bb.z, 0.f));
    o.w = f2bf(fmaxf((v.w - mu.w) * rs.w * gg.w + bb.w, 0.f));
    *(ushort4*)&xo[e0] = o;
    if (zero_y)
        *(float4*)&y[e0] = make_float4(0.f, 0.f, 0.f, 0.f);
}

// ---------------------------------------------------------------------------
extern "C" void kernel_launch(void* const* d_in, const int* in_sizes, int n_in,
                              void* d_out, int out_size, void* d_ws, size_t ws_size,
                              hipStream_t stream) {
    const float* feat0   = (const float*)d_in[0];
    const float* feat1   = (const float*)d_in[1];
    const float* feat2   = (const float*)d_in[2];
    const float* bbox2d  = (const float*)d_in[3];
    const int*   anchor  = (const int*)d_in[4];
    const float* fc1_w   = (const float*)d_in[5];
    const float* bn1_g   = (const float*)d_in[7];
    const float* bn1_b   = (const float*)d_in[8];
    const float* fc2_w   = (const float*)d_in[9];
    const float* bn2_g   = (const float*)d_in[11];
    const float* bn2_b   = (const float*)d_in[12];
    const float* cate_w  = (const float*)d_in[13];
    const float* cate_b  = (const float*)d_in[14];
    const float* bbox3d_w= (const float*)d_in[15];
    const float* bbox3d_b= (const float*)d_in[16];
    const float* yawc_w  = (const float*)d_in[17];
    const float* yawc_b  = (const float*)d_in[18];
    const float* yawr_w  = (const float*)d_in[19];
    const float* yawr_b  = (const float*)d_in[20];
    const float* hgt_w   = (const float*)d_in[21];
    const float* hgt_b   = (const float*)d_in[22];

    const int B = 4, N = 512, FC = 1024;
    const int M = B * N;   // 2048
    const int K1 = 12544;  // 256*49

    // workspace layout (tf* aliased with post-ROI buffers; disjoint lifetimes)
    char* base = (char*)d_ws;
    u16* xb = (u16*)base;                              // 51,380,224 B
    char* ub = base + 51380224;                        // union, 44,040,192 B
    u16* tf0 = (u16*)ub;                               // 33,554,432
    u16* tf1 = (u16*)(ub + 33554432);                  //  8,388,608
    u16* tf2 = (u16*)(ub + 41943040);                  //  2,097,152
    u16* w1t = (u16*)ub;                               // 25,690,112
    u16* w2t = (u16*)(ub + 25690112);                  //  2,097,152
    float* y   = (float*)(ub + 27787264);              //  8,388,608
    u16* x1b = (u16*)(ub + 36175872);                  //  4,194,304 (end 40,370,176)
    float* part = (float*)(ub + 40370176);             //    524,288 (end 40,894,464)
    char* tail = ub + 44040192;
    float* stats = (float*)tail;                       // 8 KB
    u16*   whT   = (u16*)(tail + 8192);                // 262,144 (128x1024 bf16)
    float* outp  = (float*)d_out;

    // 1. head prep: whT concat + bias broadcast straight into d_out
    head_prep_kernel<<<(M * 100 + 255) / 256, 256, 0, stream>>>(
        cate_w, bbox3d_w, yawc_w, yawr_w, hgt_w,
        cate_b, bbox3d_b, yawc_b, yawr_b, hgt_b, whT, outp);

    // 2. fused feature layout transform (B,C,H,W)f32 -> (B,HW,C)bf16
    transpose_feat3_kernel<<<dim3(336, B), 256, 0, stream>>>(
        feat0, feat1, feat2, tf0, tf1, tf2);

    // 3. ROI align -> x bf16 (M, K1), k' = bin*256 + c layout
    roi_align_v3_kernel<<<M, 512, 0, stream>>>(tf0, tf1, tf2, bbox2d, anchor, xb);

    // 4. merged weight transposes (overwrite tf* region — after roi);
    //    also zeroes y (replaces memset launch)
    transpose_w2_kernel<<<dim3(212, FC / 64), 256, 0, stream>>>(
        fc1_w, fc2_w, w1t, w2t, (float4*)y);

    // 5. fc1 (128^2 split-K=4 — best measured config) + BN1
    gemm_splitk_kernel<<<dim3(M / 128, FC / 128, 4), 256, 0, stream>>>(
        xb, w1t, y, FC, FC, K1, K1 / 4);
    bn_stats_part_kernel<<<dim3(FC / 256, M / 32), 256, 0, stream>>>(y, part, FC);
    bn_stats_final_kernel<<<FC / 256, 256, 0, stream>>>(part, stats, M, M / 32);
    bn_apply_kernel<<<(M * FC / 4 + 255) / 256, 256, 0, stream>>>(
        y, stats, bn1_g, bn1_b, x1b, M * FC / 4, 1);  // zero y for fc2

    // 6. fc2 (split-K=4) + BN2
    gemm_splitk_kernel<<<dim3(M / 128, FC / 128, 4), 256, 0, stream>>>(
        x1b, w2t, y, FC, FC, FC, FC / 4);
    bn_stats_part_kernel<<<dim3(FC / 256, M / 32), 256, 0, stream>>>(y, part, FC);
    bn_stats_final_kernel<<<FC / 256, 256, 0, stream>>>(part, stats, M, M / 32);
    bn_apply_kernel<<<(M * FC / 4 + 255) / 256, 256, 0, stream>>>(
        y, stats, bn2_g, bn2_b, x1b, M * FC / 4, 0);

    // 7. heads: out(bias-preloaded) += (x1b @ whT^T)[:, :100]
    gemm_splitk_kernel<<<dim3(M / 128, 1, 16), 256, 0, stream>>>(
        x1b, whT, outp, 100, 100, FC, FC / 16);
}